// Round 1
// baseline (570.089 us; speedup 1.0000x reference)
//
#include <hip/hip_runtime.h>
#include <cstdint>
#include <cstddef>

// Fused LN + QKV + 4-token/2-head attention + out-proj + residual for MI355X.
// One block = 512 threads (8 waves) handles 16 groups (64 rows of 256).
// bf16 MFMA (16x16x32) for both GEMMs, fp32 accumulate; attention in fp32 VALU.
// Heads processed sequentially so the qkv intermediate fits in LDS.

typedef __attribute__((ext_vector_type(8))) short short8;
typedef __attribute__((ext_vector_type(8))) unsigned short ushort8;
typedef __attribute__((ext_vector_type(4))) float floatx4;

#define DIM   256
#define HD    128
#define NH    2
#define ROWS  64            // rows per block (16 groups x 4 tokens)
#define XN_S  264           // xn LDS row stride (bf16 elems; 256+8 pad -> 2-way max on b128)
#define QK_S  392           // qkv-half row stride (384+8)
#define O_S   264           // O row stride
#define SCALE 0.08838834764831845f   // 128^-0.5

__device__ __forceinline__ unsigned short f2bf(float f) {
  unsigned int u = __builtin_bit_cast(unsigned int, f);
  u += 0x7fffu + ((u >> 16) & 1u);          // round-to-nearest-even
  return (unsigned short)(u >> 16);
}
__device__ __forceinline__ float bf2f(unsigned short h) {
  return __builtin_bit_cast(float, (unsigned int)h << 16);
}
__device__ __forceinline__ short8 pack8(float4 a, float4 b) {
  ushort8 u;
  u[0] = f2bf(a.x); u[1] = f2bf(a.y); u[2] = f2bf(a.z); u[3] = f2bf(a.w);
  u[4] = f2bf(b.x); u[5] = f2bf(b.y); u[6] = f2bf(b.z); u[7] = f2bf(b.w);
  return __builtin_bit_cast(short8, u);
}

__global__ __launch_bounds__(512) void fused_group_attn(
    const float* __restrict__ x, const float* __restrict__ qkv_w,
    const float* __restrict__ qkv_b, const float* __restrict__ out_w,
    const float* __restrict__ out_b, const float* __restrict__ ln_g,
    const float* __restrict__ ln_b, float* __restrict__ out) {
  __shared__ unsigned short xn[ROWS * XN_S];      // LayerNormed x, bf16
  __shared__ unsigned short qkvh[ROWS * QK_S];    // q|k|v for current head, bf16
  __shared__ unsigned short Obuf[ROWS * O_S];     // attention output, bf16

  const int tid  = threadIdx.x;
  const int lane = tid & 63;
  const int wid  = tid >> 6;          // 0..7
  const int quad = lane >> 4;         // 0..3
  const int l15  = lane & 15;
  const size_t rowbase = (size_t)blockIdx.x * ROWS;

  // ---------- Phase 1: load x, LayerNorm, store xn (bf16) ----------
  {
    const int row = tid >> 3;         // 0..63 (8 threads per row)
    const int seg = tid & 7;          // each covers 32 cols
    const float* xr = x + (rowbase + row) * DIM + seg * 32;
    const float4* xr4 = reinterpret_cast<const float4*>(xr);
    float4 v[8];
    float s = 0.f, sq = 0.f;
#pragma unroll
    for (int i = 0; i < 8; ++i) {
      v[i] = xr4[i];
      s  += v[i].x + v[i].y + v[i].z + v[i].w;
      sq += v[i].x * v[i].x + v[i].y * v[i].y + v[i].z * v[i].z + v[i].w * v[i].w;
    }
#pragma unroll
    for (int off = 1; off < 8; off <<= 1) {   // reduce across the 8 lanes of this row
      s  += __shfl_xor(s, off);
      sq += __shfl_xor(sq, off);
    }
    const float mu   = s * (1.f / DIM);
    const float var  = sq * (1.f / DIM) - mu * mu;
    const float rstd = rsqrtf(var + 1e-5f);
    const float4* g4 = reinterpret_cast<const float4*>(ln_g + seg * 32);
    const float4* b4 = reinterpret_cast<const float4*>(ln_b + seg * 32);
#pragma unroll
    for (int p = 0; p < 4; ++p) {
      float4 ga = g4[2 * p], gb = g4[2 * p + 1];
      float4 ba = b4[2 * p], bb = b4[2 * p + 1];
      float4 va = v[2 * p],  vb = v[2 * p + 1];
      ushort8 o;
      o[0] = f2bf((va.x - mu) * rstd * ga.x + ba.x);
      o[1] = f2bf((va.y - mu) * rstd * ga.y + ba.y);
      o[2] = f2bf((va.z - mu) * rstd * ga.z + ba.z);
      o[3] = f2bf((va.w - mu) * rstd * ga.w + ba.w);
      o[4] = f2bf((vb.x - mu) * rstd * gb.x + bb.x);
      o[5] = f2bf((vb.y - mu) * rstd * gb.y + bb.y);
      o[6] = f2bf((vb.z - mu) * rstd * gb.z + bb.z);
      o[7] = f2bf((vb.w - mu) * rstd * gb.w + bb.w);
      *reinterpret_cast<ushort8*>(&xn[row * XN_S + seg * 32 + p * 8]) = o;
    }
  }

  // ---------- Phase 2: per head, QKV half-GEMM then attention ----------
  for (int h = 0; h < NH; ++h) {
    __syncthreads();   // h=0: xn ready; h>0: previous attention done reading qkvh

    // QKV GEMM for this head: 24 n-tiles (q:8, k:8, v:8), 3 per wave.
#pragma unroll
    for (int i = 0; i < 3; ++i) {
      const int nt   = wid * 3 + i;      // 0..23
      const int s    = nt >> 3;          // 0=q 1=k 2=v
      const int w16  = nt & 7;
      const int wrow = s * 256 + h * HD + w16 * 16 + l15;   // row of qkv_w = output col
      const float* wp = qkv_w + (size_t)wrow * DIM + quad * 8;
      floatx4 acc[4];
#pragma unroll
      for (int m = 0; m < 4; ++m) acc[m] = (floatx4){0.f, 0.f, 0.f, 0.f};
#pragma unroll
      for (int k = 0; k < 8; ++k) {
        float4 wa = *reinterpret_cast<const float4*>(wp + k * 32);
        float4 wb = *reinterpret_cast<const float4*>(wp + k * 32 + 4);
        short8 bfrag = pack8(wa, wb);
#pragma unroll
        for (int m = 0; m < 4; ++m) {
          short8 afrag = *reinterpret_cast<const short8*>(
              &xn[(m * 16 + l15) * XN_S + k * 32 + quad * 8]);
          acc[m] = __builtin_amdgcn_mfma_f32_16x16x32_bf16(afrag, bfrag, acc[m], 0, 0, 0);
        }
      }
      const float bias = qkv_b[wrow];
      const int lcol = s * HD + w16 * 16 + l15;   // col inside qkvh
#pragma unroll
      for (int m = 0; m < 4; ++m)
#pragma unroll
        for (int r = 0; r < 4; ++r)
          qkvh[(m * 16 + quad * 4 + r) * QK_S + lcol] = f2bf(acc[m][r] + bias);
    }
    __syncthreads();

    // Attention for this head: 16 groups, 2 per wave.
#pragma unroll
    for (int gi = 0; gi < 2; ++gi) {
      const int g = wid * 2 + gi;
      // S[t][u]: 16 (t,u) pairs x 4 chunk-lanes of 32 elems each
      const int t = (lane & 15) >> 2, u = lane & 3, cq = lane >> 4;
      const unsigned short* qp = &qkvh[(4 * g + t) * QK_S + cq * 32];
      const unsigned short* kp = &qkvh[(4 * g + u) * QK_S + 128 + cq * 32];
      float sdot = 0.f;
#pragma unroll
      for (int j = 0; j < 4; ++j) {
        ushort8 qv = *reinterpret_cast<const ushort8*>(qp + j * 8);
        ushort8 kv = *reinterpret_cast<const ushort8*>(kp + j * 8);
#pragma unroll
        for (int e = 0; e < 8; ++e) sdot += bf2f(qv[e]) * bf2f(kv[e]);
      }
      sdot += __shfl_xor(sdot, 16);
      sdot += __shfl_xor(sdot, 32);      // all lanes now hold full S[t][u]
      sdot *= SCALE;
      float mx = fmaxf(sdot, __shfl_xor(sdot, 1));
      mx = fmaxf(mx, __shfl_xor(mx, 2));
      float ex = __expf(sdot - mx);
      float den = ex + __shfl_xor(ex, 1);
      den += __shfl_xor(den, 2);
      const float p = ex / den;          // P[t][u], replicated across quads

      // O[t2][d] = sum_u P[t2][u] * V[u][d]; lane: t2=quad, d-chunk of 8
      const int t2 = quad, d0 = l15 * 8;
      float o[8];
#pragma unroll
      for (int e = 0; e < 8; ++e) o[e] = 0.f;
#pragma unroll
      for (int uu = 0; uu < 4; ++uu) {
        const float pu = __shfl(p, t2 * 4 + uu);   // from quad 0
        ushort8 vv = *reinterpret_cast<const ushort8*>(
            &qkvh[(4 * g + uu) * QK_S + 256 + d0]);
#pragma unroll
        for (int e = 0; e < 8; ++e) o[e] += pu * bf2f(vv[e]);
      }
      ushort8 ov;
#pragma unroll
      for (int e = 0; e < 8; ++e) ov[e] = f2bf(o[e]);
      *reinterpret_cast<ushort8*>(&Obuf[(4 * g + t2) * O_S + h * HD + d0]) = ov;
    }
  }
  __syncthreads();   // Obuf complete (both heads)

  // ---------- Phase 3: out-proj GEMM + bias + residual ----------
#pragma unroll
  for (int i = 0; i < 2; ++i) {
    const int nt   = wid * 2 + i;         // 0..15
    const int ocol = nt * 16 + l15;
    const float* wp = out_w + (size_t)ocol * DIM + quad * 8;
    floatx4 acc[4];
#pragma unroll
    for (int m = 0; m < 4; ++m) acc[m] = (floatx4){0.f, 0.f, 0.f, 0.f};
#pragma unroll
    for (int k = 0; k < 8; ++k) {
      float4 wa = *reinterpret_cast<const float4*>(wp + k * 32);
      float4 wb = *reinterpret_cast<const float4*>(wp + k * 32 + 4);
      short8 bfrag = pack8(wa, wb);
#pragma unroll
      for (int m = 0; m < 4; ++m) {
        short8 afrag = *reinterpret_cast<const short8*>(
            &Obuf[(m * 16 + l15) * O_S + k * 32 + quad * 8]);
        acc[m] = __builtin_amdgcn_mfma_f32_16x16x32_bf16(afrag, bfrag, acc[m], 0, 0, 0);
      }
    }
    const float bias = out_b[ocol];
#pragma unroll
    for (int m = 0; m < 4; ++m)
#pragma unroll
      for (int r = 0; r < 4; ++r) {
        const size_t gidx = (rowbase + m * 16 + quad * 4 + r) * DIM + ocol;
        out[gidx] = acc[m][r] + bias + x[gidx];   // residual re-read (L2-hot)
      }
  }
}

extern "C" void kernel_launch(void* const* d_in, const int* in_sizes, int n_in,
                              void* d_out, int out_size, void* d_ws, size_t ws_size,
                              hipStream_t stream) {
  const float* x     = (const float*)d_in[0];
  const float* qkv_w = (const float*)d_in[1];
  const float* qkv_b = (const float*)d_in[2];
  const float* out_w = (const float*)d_in[3];
  const float* out_b = (const float*)d_in[4];
  const float* ln_g  = (const float*)d_in[5];
  const float* ln_b  = (const float*)d_in[6];
  float* out = (float*)d_out;
  const int rows = in_sizes[0] / DIM;     // 131072
  const int nblk = rows / ROWS;           // 2048
  hipLaunchKernelGGL(fused_group_attn, dim3(nblk), dim3(512), 0, stream,
                     x, qkv_w, qkv_b, out_w, out_b, ln_g, ln_b, out);
}

// Round 2
// 339.514 us; speedup vs baseline: 1.6791x; 1.6791x over previous
//
#include <hip/hip_runtime.h>
#include <cstdint>
#include <cstddef>

// Fused LN + QKV + 4-token/2-head attention + out-proj + residual, MI355X.
// R2: weights pre-converted to bf16 MFMA-fragment layout in __device__ bufs
// (one tiny kernel per launch); ROWS=32 + full-qkv LDS (65 KB) -> 2 blocks/CU;
// k-outer GEMM with register-cached A-fragments.

typedef __attribute__((ext_vector_type(8))) short short8;
typedef __attribute__((ext_vector_type(8))) unsigned short ushort8;
typedef __attribute__((ext_vector_type(4))) float floatx4;

#define DIM    256
#define HD     128
#define ROWS   32            // rows per block (8 groups x 4 tokens)
#define XN_S   264           // xn / O LDS row stride (256+8)
#define QKV_S  776           // qkv LDS row stride (768+8)
#define NT_QKV 48            // 768/16 n-tiles
#define NT_OP  16            // 256/16 n-tiles
#define SCALE  0.08838834764831845f   // 128^-0.5

// bf16 weights in MFMA B-fragment order: [nt][k][lane][8]
__device__ unsigned short g_qkvw[NT_QKV * 8 * 64 * 8];   // 196608
__device__ unsigned short g_outw[NT_OP * 8 * 64 * 8];    //  65536

__device__ __forceinline__ unsigned short f2bf(float f) {
  unsigned int u = __builtin_bit_cast(unsigned int, f);
  u += 0x7fffu + ((u >> 16) & 1u);          // RNE
  return (unsigned short)(u >> 16);
}
__device__ __forceinline__ float bf2f(unsigned short h) {
  return __builtin_bit_cast(float, (unsigned int)h << 16);
}

__global__ __launch_bounds__(256) void convert_weights(
    const float* __restrict__ qkv_w, const float* __restrict__ out_w) {
  const int id = blockIdx.x * 256 + threadIdx.x;   // 0..32767
  const float* src;
  unsigned short* dst;
  if (id < NT_QKV * 8 * 64) {
    const int nt = id >> 9, k = (id >> 6) & 7, lane = id & 63;
    src = qkv_w + (size_t)(nt * 16 + (lane & 15)) * DIM + k * 32 + (lane >> 4) * 8;
    dst = g_qkvw + (size_t)id * 8;
  } else {
    const int id2 = id - NT_QKV * 8 * 64;
    const int nt = id2 >> 9, k = (id2 >> 6) & 7, lane = id2 & 63;
    src = out_w + (size_t)(nt * 16 + (lane & 15)) * DIM + k * 32 + (lane >> 4) * 8;
    dst = g_outw + (size_t)id2 * 8;
  }
  float4 a = *reinterpret_cast<const float4*>(src);
  float4 b = *reinterpret_cast<const float4*>(src + 4);
  ushort8 o;
  o[0] = f2bf(a.x); o[1] = f2bf(a.y); o[2] = f2bf(a.z); o[3] = f2bf(a.w);
  o[4] = f2bf(b.x); o[5] = f2bf(b.y); o[6] = f2bf(b.z); o[7] = f2bf(b.w);
  *reinterpret_cast<ushort8*>(dst) = o;
}

__global__ __launch_bounds__(512, 4) void fused_group_attn(
    const float* __restrict__ x,
    const float* __restrict__ qkv_b, const float* __restrict__ out_b,
    const float* __restrict__ ln_g, const float* __restrict__ ln_b,
    float* __restrict__ out) {
  __shared__ unsigned short xn[ROWS * XN_S];     // LN output; reused for O
  __shared__ unsigned short qkv[ROWS * QKV_S];   // q|k|v bf16

  const int tid  = threadIdx.x;
  const int lane = tid & 63;
  const int wid  = tid >> 6;          // 0..7
  const int quad = lane >> 4;         // 0..3
  const int l15  = lane & 15;
  const size_t rowbase = (size_t)blockIdx.x * ROWS;

  // ---------- P1: load x, LayerNorm -> xn (bf16) ----------
  {
    const int row = tid >> 4;         // 0..31 (16 threads per row)
    const int seg = tid & 15;         // 16 cols each
    const float4* xr4 = reinterpret_cast<const float4*>(
        x + (rowbase + row) * DIM + seg * 16);
    float4 v[4];
    float s = 0.f, sq = 0.f;
#pragma unroll
    for (int i = 0; i < 4; ++i) {
      v[i] = xr4[i];
      s  += v[i].x + v[i].y + v[i].z + v[i].w;
      sq += v[i].x * v[i].x + v[i].y * v[i].y + v[i].z * v[i].z + v[i].w * v[i].w;
    }
#pragma unroll
    for (int off = 1; off < 16; off <<= 1) {
      s  += __shfl_xor(s, off);
      sq += __shfl_xor(sq, off);
    }
    const float mu   = s * (1.f / DIM);
    const float var  = sq * (1.f / DIM) - mu * mu;
    const float rstd = rsqrtf(var + 1e-5f);
    const float4* g4 = reinterpret_cast<const float4*>(ln_g + seg * 16);
    const float4* b4 = reinterpret_cast<const float4*>(ln_b + seg * 16);
#pragma unroll
    for (int p = 0; p < 2; ++p) {
      float4 ga = g4[2 * p], gb = g4[2 * p + 1];
      float4 ba = b4[2 * p], bb = b4[2 * p + 1];
      float4 va = v[2 * p],  vb = v[2 * p + 1];
      ushort8 o;
      o[0] = f2bf((va.x - mu) * rstd * ga.x + ba.x);
      o[1] = f2bf((va.y - mu) * rstd * ga.y + ba.y);
      o[2] = f2bf((va.z - mu) * rstd * ga.z + ba.z);
      o[3] = f2bf((va.w - mu) * rstd * ga.w + ba.w);
      o[4] = f2bf((vb.x - mu) * rstd * gb.x + bb.x);
      o[5] = f2bf((vb.y - mu) * rstd * gb.y + bb.y);
      o[6] = f2bf((vb.z - mu) * rstd * gb.z + bb.z);
      o[7] = f2bf((vb.w - mu) * rstd * gb.w + bb.w);
      *reinterpret_cast<ushort8*>(&xn[row * XN_S + seg * 16 + p * 8]) = o;
    }
  }
  __syncthreads();

  // ---------- P2: QKV GEMM (48 n-tiles, 6/wave; 2 m-tiles) ----------
  {
    floatx4 acc[6][2];
#pragma unroll
    for (int n = 0; n < 6; ++n)
#pragma unroll
      for (int m = 0; m < 2; ++m) acc[n][m] = (floatx4){0.f, 0.f, 0.f, 0.f};
#pragma unroll
    for (int k = 0; k < 8; ++k) {
      short8 a0 = *reinterpret_cast<const short8*>(&xn[l15 * XN_S + k * 32 + quad * 8]);
      short8 a1 = *reinterpret_cast<const short8*>(&xn[(16 + l15) * XN_S + k * 32 + quad * 8]);
#pragma unroll
      for (int n = 0; n < 6; ++n) {
        short8 b = *reinterpret_cast<const short8*>(
            g_qkvw + (size_t)(((wid * 6 + n) * 8 + k) * 64 + lane) * 8);
        acc[n][0] = __builtin_amdgcn_mfma_f32_16x16x32_bf16(a0, b, acc[n][0], 0, 0, 0);
        acc[n][1] = __builtin_amdgcn_mfma_f32_16x16x32_bf16(a1, b, acc[n][1], 0, 0, 0);
      }
    }
#pragma unroll
    for (int n = 0; n < 6; ++n) {
      const int col = (wid * 6 + n) * 16 + l15;
      const float bias = qkv_b[col];
#pragma unroll
      for (int m = 0; m < 2; ++m)
#pragma unroll
        for (int r = 0; r < 4; ++r)
          qkv[(m * 16 + quad * 4 + r) * QKV_S + col] = f2bf(acc[n][m][r] + bias);
    }
  }
  __syncthreads();

  // ---------- P3: attention, one group per wave; lanes split by head ----------
  {
    const int g    = wid;             // group 0..7 (rows 4g..4g+3)
    const int half = lane >> 5;       // head
    const int l5   = lane & 31;
    const int t = (l5 & 15) >> 2, u = l5 & 3, c = l5 >> 4;
    const unsigned short* qp = &qkv[(4 * g + t) * QKV_S + half * HD + c * 64];
    const unsigned short* kp = &qkv[(4 * g + u) * QKV_S + 256 + half * HD + c * 64];
    float sdot = 0.f;
#pragma unroll
    for (int j = 0; j < 8; ++j) {
      ushort8 qv = *reinterpret_cast<const ushort8*>(qp + j * 8);
      ushort8 kv = *reinterpret_cast<const ushort8*>(kp + j * 8);
#pragma unroll
      for (int e = 0; e < 8; ++e) sdot += bf2f(qv[e]) * bf2f(kv[e]);
    }
    sdot += __shfl_xor(sdot, 16);     // combine the two 64-elem chunks
    sdot *= SCALE;
    float mx = fmaxf(sdot, __shfl_xor(sdot, 1));
    mx = fmaxf(mx, __shfl_xor(mx, 2));
    float ex = __expf(sdot - mx);
    float den = ex + __shfl_xor(ex, 1);
    den += __shfl_xor(den, 2);
    const float p = ex / den;         // P[t][u] replicated on c=0/1

    // PV: t2 = l5>>3, 16-col segment per lane
    const int t2 = l5 >> 3, dseg = l5 & 7;
    float o[16];
#pragma unroll
    for (int e = 0; e < 16; ++e) o[e] = 0.f;
#pragma unroll
    for (int uu = 0; uu < 4; ++uu) {
      const float pu = __shfl(p, (lane & 32) + t2 * 4 + uu);
      const unsigned short* vp = &qkv[(4 * g + uu) * QKV_S + 512 + half * HD + dseg * 16];
      ushort8 v0 = *reinterpret_cast<const ushort8*>(vp);
      ushort8 v1 = *reinterpret_cast<const ushort8*>(vp + 8);
#pragma unroll
      for (int e = 0; e < 8; ++e) {
        o[e]     += pu * bf2f(v0[e]);
        o[e + 8] += pu * bf2f(v1[e]);
      }
    }
    ushort8 w0, w1;
#pragma unroll
    for (int e = 0; e < 8; ++e) { w0[e] = f2bf(o[e]); w1[e] = f2bf(o[e + 8]); }
    unsigned short* op = &xn[(4 * g + t2) * XN_S + half * HD + dseg * 16];
    *reinterpret_cast<ushort8*>(op)     = w0;
    *reinterpret_cast<ushort8*>(op + 8) = w1;
  }
  __syncthreads();

  // ---------- P4: out-proj GEMM + bias + residual ----------
  {
    floatx4 acc[2][2];
#pragma unroll
    for (int n = 0; n < 2; ++n)
#pragma unroll
      for (int m = 0; m < 2; ++m) acc[n][m] = (floatx4){0.f, 0.f, 0.f, 0.f};
#pragma unroll
    for (int k = 0; k < 8; ++k) {
      short8 a0 = *reinterpret_cast<const short8*>(&xn[l15 * XN_S + k * 32 + quad * 8]);
      short8 a1 = *reinterpret_cast<const short8*>(&xn[(16 + l15) * XN_S + k * 32 + quad * 8]);
#pragma unroll
      for (int n = 0; n < 2; ++n) {
        short8 b = *reinterpret_cast<const short8*>(
            g_outw + (size_t)(((wid * 2 + n) * 8 + k) * 64 + lane) * 8);
        acc[n][0] = __builtin_amdgcn_mfma_f32_16x16x32_bf16(a0, b, acc[n][0], 0, 0, 0);
        acc[n][1] = __builtin_amdgcn_mfma_f32_16x16x32_bf16(a1, b, acc[n][1], 0, 0, 0);
      }
    }
#pragma unroll
    for (int n = 0; n < 2; ++n) {
      const int col = (wid * 2 + n) * 16 + l15;
      const float bias = out_b[col];
#pragma unroll
      for (int m = 0; m < 2; ++m)
#pragma unroll
        for (int r = 0; r < 4; ++r) {
          const size_t gidx = (rowbase + m * 16 + quad * 4 + r) * DIM + col;
          out[gidx] = acc[n][m][r] + bias + x[gidx];
        }
    }
  }
}

extern "C" void kernel_launch(void* const* d_in, const int* in_sizes, int n_in,
                              void* d_out, int out_size, void* d_ws, size_t ws_size,
                              hipStream_t stream) {
  const float* x     = (const float*)d_in[0];
  const float* qkv_w = (const float*)d_in[1];
  const float* qkv_b = (const float*)d_in[2];
  const float* out_w = (const float*)d_in[3];
  const float* out_b = (const float*)d_in[4];
  const float* ln_g  = (const float*)d_in[5];
  const float* ln_b  = (const float*)d_in[6];
  float* out = (float*)d_out;

  hipLaunchKernelGGL(convert_weights, dim3(128), dim3(256), 0, stream, qkv_w, out_w);

  const int rows = in_sizes[0] / DIM;     // 131072
  const int nblk = rows / ROWS;           // 4096
  hipLaunchKernelGGL(fused_group_attn, dim3(nblk), dim3(512), 0, stream,
                     x, qkv_b, out_b, ln_g, ln_b, out);
}